// Round 2
// baseline (676.478 us; speedup 1.0000x reference)
//
#include <hip/hip_runtime.h>

#define NB 32
#define NN 256
#define NI 16
#define NO 16
#define NC 64
#define NH 64
#define NE 4096

__device__ __forceinline__ float sigmoidf_(float x){ return 1.0f/(1.0f+__expf(-x)); }
__device__ __forceinline__ float tanhf_(float x){
  float e = __expf(2.0f*x);              // inf for big x -> 1.0; 0 for very neg -> -1.0
  return 1.0f - 2.0f/(e+1.0f);
}

// ---- runtime dtype detection ------------------------------------------------
// flags[0] != 0  -> masks are 1-byte bools; == 0 -> int32
// flags[1] != 0  -> edge_index is int32;    == 0 -> int64
__global__ void k_detect(const unsigned char* __restrict__ m8, const int* __restrict__ ei, int* flags){
  int t = blockIdx.x*256 + threadIdx.x;              // 32768 threads
  unsigned a = (unsigned)m8[t*4+1] | (unsigned)m8[t*4+2] | (unsigned)m8[t*4+3];
  if (__any(a != 0) && (threadIdx.x & 63) == 0) atomicOr(&flags[0], 1);
  unsigned b = 0;
  if (t < 4096) b = (unsigned)ei[2*t+1];
  if (__any(b != 0) && (threadIdx.x & 63) == 0) atomicOr(&flags[1], 1);
}

// ---- mask -------------------------------------------------------------------
__global__ void k_mask(const float* __restrict__ data, const unsigned char* __restrict__ m8,
                       const int* __restrict__ flags, float* __restrict__ dm){
  int i = blockIdx.x*256 + threadIdx.x;              // 131072
  int mv = flags[0] ? (int)m8[i] : ((const int*)m8)[i];
  dm[i] = mv ? data[i] : 0.0f;
}

__device__ __forceinline__ int edge_src(const int* ei, const int* flags, int e){
  return flags[1] ? ei[e] : ei[2*e];
}
__device__ __forceinline__ int edge_dst(const int* ei, const int* flags, int e){
  return flags[1] ? ei[NE + e] : ei[2*(NE + e)];
}

// ---- GCN graph prep: degree -> dinv -> weighted adjacency (one block) --------
// wadj must be pre-zeroed.
__global__ __launch_bounds__(256) void k_graph(const int* __restrict__ ei, const int* __restrict__ flags,
                                               float* wadj){
  __shared__ float degs[NN];
  __shared__ float dls[NN];
  int t = threadIdx.x;
  degs[t] = 0.f;
  __syncthreads();
  #pragma unroll
  for (int e = t; e < NE; e += 256) atomicAdd(&degs[edge_dst(ei, flags, e)], 1.0f);
  __syncthreads();
  float di = rsqrtf(degs[t] + 2.0f);
  dls[t] = di;
  atomicAdd(&wadj[t*NN + t], 2.0f*di*di);            // improved self-loop
  __syncthreads();
  #pragma unroll
  for (int e = t; e < NE; e += 256){
    int s = edge_src(ei, flags, e), d = edge_dst(ei, flags, e);
    atomicAdd(&wadj[d*NN + s], dls[s]*dls[d]);
  }
}

// ---- xw = x @ gcn_w ----------------------------------------------------------
__global__ void k_xw(const float* __restrict__ dm, const float* __restrict__ gw, float* __restrict__ xw){
  int idx = blockIdx.x*256 + threadIdx.x;            // 524288
  int c = idx & 63, n = (idx>>6) & 255, b = idx>>14;
  const float* dmb = dm + b*NI*NN;
  float a = 0.f;
  #pragma unroll
  for (int i=0;i<NI;i++) a += dmb[i*NN + n]*gw[i*NC + c];
  xw[idx] = a;
}

// ---- h = relu(W_adj @ xw + b) -------------------------------------------------
__global__ void k_agg(const float* __restrict__ wadj, const float* __restrict__ xw,
                      const float* __restrict__ gb, float* __restrict__ h){
  int idx = blockIdx.x*256 + threadIdx.x;            // 524288
  int c = idx & 63, n = (idx>>6) & 255, b = idx>>14;
  const float* wr = wadj + n*NN;
  const float* xb = xw + b*NN*NC + c;
  float a = gb[c];
  #pragma unroll 4
  for (int m=0;m<NN;m++) a += wr[m]*xb[m*NC];
  h[idx] = fmaxf(a, 0.0f);
}

// ---- q,k projections (shared by spatial & temporal attention) ------------------
__global__ void k_qk(const float* __restrict__ src, const float* __restrict__ qw,
                     const float* __restrict__ qbias, const float* __restrict__ kw,
                     const float* __restrict__ kbias, float* __restrict__ q, float* __restrict__ kout){
  int idx = blockIdx.x*256 + threadIdx.x;            // 524288
  int c = idx & 63;
  const float* hr = src + (idx>>6)*NC;
  float aq = qbias[c], ak = kbias[c];
  #pragma unroll 8
  for (int cc=0; cc<NC; cc++){ float hv = hr[cc]; aq += hv*qw[cc*NC + c]; ak += hv*kw[cc*NC + c]; }
  q[idx] = aq; kout[idx] = ak;
}

// ---- fused attention: 8 query rows per block, transposed output write ---------
__global__ __launch_bounds__(256) void k_attn8(const float* __restrict__ q, const float* __restrict__ kmat,
                        const float* __restrict__ v, float* __restrict__ outp, float scale){
  int bidx = blockIdx.x; int b = bidx >> 5, n0 = (bidx & 31)*8;
  int t = threadIdx.x;
  __shared__ __align__(16) float qs[8][64];
  __shared__ float S[8][256];
  #pragma unroll
  for (int rep=0; rep<2; rep++){
    int j = rep*256 + t; int r = j>>6, c = j&63;
    qs[r][c] = q[((b<<8) + n0 + r)*NC + c];
  }
  __syncthreads();
  float4 kr[16];
  const float4* kp = (const float4*)(kmat + ((b<<8) + t)*NC);
  #pragma unroll
  for (int i=0;i<16;i++) kr[i] = kp[i];
  #pragma unroll
  for (int r=0;r<8;r++){
    const float4* q4 = (const float4*)qs[r];
    float s = 0.f;
    #pragma unroll
    for (int i=0;i<16;i++){ float4 a=q4[i], bb=kr[i]; s += a.x*bb.x + a.y*bb.y + a.z*bb.z + a.w*bb.w; }
    S[r][t] = s*scale;
  }
  __syncthreads();
  {
    int g = t>>5, l = t&31;
    float vals[8];
    #pragma unroll
    for (int k2=0;k2<8;k2++) vals[k2] = S[g][l + (k2<<5)];
    float mx = vals[0];
    #pragma unroll
    for (int k2=1;k2<8;k2++) mx = fmaxf(mx, vals[k2]);
    #pragma unroll
    for (int off=16; off; off>>=1) mx = fmaxf(mx, __shfl_xor(mx, off));
    float sm = 0.f;
    #pragma unroll
    for (int k2=0;k2<8;k2++){ vals[k2] = __expf(vals[k2]-mx); sm += vals[k2]; }
    #pragma unroll
    for (int off=16; off; off>>=1) sm += __shfl_xor(sm, off);
    float rS = 1.0f/sm;
    #pragma unroll
    for (int k2=0;k2<8;k2++) S[g][l + (k2<<5)] = vals[k2]*rS;
  }
  __syncthreads();
  int c = t & 63, rp = t >> 6;
  const float* vp = v + (b<<8)*NC + c;
  float a0 = 0.f, a1 = 0.f;
  #pragma unroll 4
  for (int m=0;m<NN;m++){
    float vv = vp[m*NC];
    a0 += S[rp][m]*vv;
    a1 += S[rp+4][m]*vv;
  }
  outp[(((b<<6)+c)<<8) + n0 + rp]     = a0;
  outp[(((b<<6)+c)<<8) + n0 + rp + 4] = a1;
}

// ---- GRU input gates (parallel over all timesteps) -----------------------------
__global__ void k_gi(const float* __restrict__ dm, const float* __restrict__ wih,
                     const float* __restrict__ bih, float* __restrict__ gi){
  int row = blockIdx.x;                              // b*256+t, grid 8192
  int j = threadIdx.x;                               // 0..191
  const float* xr = dm + row*NI;
  float a = bih[j];
  #pragma unroll
  for (int i=0;i<NI;i++) a += xr[i]*wih[j*NI + i];
  gi[row*192 + j] = a;
}

// ---- GRU sequential scan: one block per batch sample, gi prefetch pipeline -----
__global__ __launch_bounds__(192) void k_gru(const float* __restrict__ gi, const float* __restrict__ whh,
                      const float* __restrict__ bhh, float* __restrict__ rnn){
  int b = blockIdx.x, j = threadIdx.x;
  __shared__ __align__(16) float hs[64];
  __shared__ float gh[192];
  __shared__ float gis[192];
  float w[64];
  const float4* wr = (const float4*)(whh + j*NH);
  #pragma unroll
  for (int k4=0;k4<16;k4++){ float4 t4 = wr[k4]; w[4*k4]=t4.x; w[4*k4+1]=t4.y; w[4*k4+2]=t4.z; w[4*k4+3]=t4.w; }
  float bj = bhh[j];
  if (j < 64) hs[j] = 0.f;
  const float* gib = gi + b*NN*192;
  float pre = gib[j];                                // step-0 gates
  __syncthreads();
  for (int t=0;t<NN;t++){
    gis[j] = pre;
    if (t+1 < NN) pre = gib[(t+1)*192 + j];          // prefetch next step (latency hidden)
    float a0=0.f,a1=0.f,a2=0.f,a3=0.f;
    #pragma unroll
    for (int k4=0;k4<16;k4++){
      float4 hv = *(const float4*)&hs[4*k4];
      a0 += w[4*k4+0]*hv.x; a1 += w[4*k4+1]*hv.y; a2 += w[4*k4+2]*hv.z; a3 += w[4*k4+3]*hv.w;
    }
    gh[j] = a0+a1+a2+a3+bj;
    __syncthreads();
    if (j < 64){
      float r  = sigmoidf_(gis[j]     + gh[j]);
      float z  = sigmoidf_(gis[j+64]  + gh[j+64]);
      float nn = tanhf_   (gis[j+128] + r*gh[j+128]);
      float hn = nn + z*(hs[j]-nn);
      rnn[(b*NN + t)*NH + j] = hn;
      hs[j] = hn;
    }
    __syncthreads();
  }
}

// ---- fc1: [32,32768] @ [32768,4096] with embed-concat fused into staging -------
// grid (4, 64), block 512 (8 waves: 4 col-waves x 2 batch-halves).
// Each block: 1024 cols, 512 K-rows in 4 chunks of 128, double-buffered LDS.
#define FC1_N 4096
__device__ __forceinline__ float embed_val(const float* __restrict__ rnn, const float* __restrict__ h,
                                           int bb, int rr){
  int n = rr >> 7, c = rr & 127;
  if (c < 64) return rnn[((bb<<8) + n)*NH + c];
  int f = (n<<6) + (c-64);
  return h[(bb<<14) + ((f&255)<<6) + (f>>8)];
}

__global__ __launch_bounds__(512) void k_fc1(const float* __restrict__ W, const float* __restrict__ rnn,
                                             const float* __restrict__ h, float* __restrict__ part){
  const int tid = threadIdx.x;
  const int w = tid >> 6, lane = tid & 63;
  const int b0 = (w >> 2) * 16;                      // batch half
  const int col = blockIdx.x*1024 + (w & 3)*256 + lane*4;
  const int i0 = blockIdx.y * 512;
  __shared__ __align__(16) float es[2][128][36];     // +4 pad: 8-way instead of 32-way write conflict
  float acc[4][16];
  #pragma unroll
  for (int c=0;c<4;c++)
    #pragma unroll
    for (int bb=0;bb<16;bb++) acc[c][bb]=0.f;

  float st[8];
  // prologue: load + write chunk 0
  #pragma unroll
  for (int rep=0; rep<8; rep++){
    int x = rep*512 + tid; st[rep] = embed_val(rnn, h, x>>7, i0 + (x&127));
  }
  #pragma unroll
  for (int rep=0; rep<8; rep++){
    int x = rep*512 + tid; es[0][x&127][x>>7] = st[rep];
  }
  __syncthreads();

  for (int k=0;k<4;k++){
    const int cur = k & 1;
    if (k < 3){
      #pragma unroll
      for (int rep=0; rep<8; rep++){
        int x = rep*512 + tid; st[rep] = embed_val(rnn, h, x>>7, i0 + (k+1)*128 + (x&127));
      }
    }
    const float* wp = W + (long)(i0 + k*128)*FC1_N + col;
    #pragma unroll 4
    for (int ii=0; ii<128; ii++){
      float4 w4 = *(const float4*)(wp + (long)ii*FC1_N);
      #pragma unroll
      for (int q=0;q<4;q++){
        float4 ev = *(const float4*)&es[cur][ii][b0 + 4*q];
        acc[0][4*q+0] += w4.x*ev.x; acc[1][4*q+0] += w4.y*ev.x; acc[2][4*q+0] += w4.z*ev.x; acc[3][4*q+0] += w4.w*ev.x;
        acc[0][4*q+1] += w4.x*ev.y; acc[1][4*q+1] += w4.y*ev.y; acc[2][4*q+1] += w4.z*ev.y; acc[3][4*q+1] += w4.w*ev.y;
        acc[0][4*q+2] += w4.x*ev.z; acc[1][4*q+2] += w4.y*ev.z; acc[2][4*q+2] += w4.z*ev.z; acc[3][4*q+2] += w4.w*ev.z;
        acc[0][4*q+3] += w4.x*ev.w; acc[1][4*q+3] += w4.y*ev.w; acc[2][4*q+3] += w4.z*ev.w; acc[3][4*q+3] += w4.w*ev.w;
      }
    }
    if (k < 3){
      #pragma unroll
      for (int rep=0; rep<8; rep++){
        int x = rep*512 + tid; es[cur^1][x&127][x>>7] = st[rep];
      }
    }
    __syncthreads();
  }

  float* pp = part + (long)blockIdx.y*131072;
  #pragma unroll
  for (int bb=0;bb<16;bb++){
    float4 o; o.x=acc[0][bb]; o.y=acc[1][bb]; o.z=acc[2][bb]; o.w=acc[3][bb];
    *(float4*)&pp[(b0+bb)*FC1_N + col] = o;
  }
}

// ---- reduce fc1 partials + bias -> inter [32][4096] ---------------------------
__global__ void k_red1(const float* __restrict__ part, const float* __restrict__ bias,
                       float* __restrict__ inter){
  int idx4 = blockIdx.x*256 + threadIdx.x;           // 32768 (float4 lanes)
  float4 a = ((const float4*)bias)[idx4 & 1023];
  #pragma unroll 8
  for (int y=0;y<64;y++){
    float4 p = ((const float4*)(part + (long)y*131072))[idx4];
    a.x+=p.x; a.y+=p.y; a.z+=p.z; a.w+=p.w;
  }
  ((float4*)inter)[idx4] = a;
}

// ---- fc2: [32,4096] @ [4096,4096] ---------------------------------------------
// grid (8, 32), block 256 (4 waves: 2 col-waves x 2 batch-halves), 128 rows/block.
__global__ __launch_bounds__(256) void k_fc2(const float* __restrict__ W, const float* __restrict__ inter,
                                             float* __restrict__ part){
  const int tid = threadIdx.x;
  const int w = tid >> 6, lane = tid & 63;
  const int b0 = (w >> 1) * 16;
  const int col = blockIdx.x*512 + (w & 1)*256 + lane*4;
  const int i0 = blockIdx.y * 128;
  __shared__ __align__(16) float es[128][36];
  float acc[4][16];
  #pragma unroll
  for (int c=0;c<4;c++)
    #pragma unroll
    for (int bb=0;bb<16;bb++) acc[c][bb]=0.f;
  #pragma unroll
  for (int rep=0; rep<16; rep++){
    int x = rep*256 + tid;                           // 0..4095
    es[x&127][x>>7] = inter[(long)(x>>7)*FC1_N + i0 + (x&127)];
  }
  __syncthreads();
  const float* wp = W + (long)i0*FC1_N + col;
  #pragma unroll 4
  for (int ii=0; ii<128; ii++){
    float4 w4 = *(const float4*)(wp + (long)ii*FC1_N);
    #pragma unroll
    for (int q=0;q<4;q++){
      float4 ev = *(const float4*)&es[ii][b0 + 4*q];
      acc[0][4*q+0] += w4.x*ev.x; acc[1][4*q+0] += w4.y*ev.x; acc[2][4*q+0] += w4.z*ev.x; acc[3][4*q+0] += w4.w*ev.x;
      acc[0][4*q+1] += w4.x*ev.y; acc[1][4*q+1] += w4.y*ev.y; acc[2][4*q+1] += w4.z*ev.y; acc[3][4*q+1] += w4.w*ev.y;
      acc[0][4*q+2] += w4.x*ev.z; acc[1][4*q+2] += w4.y*ev.z; acc[2][4*q+2] += w4.z*ev.z; acc[3][4*q+2] += w4.w*ev.z;
      acc[0][4*q+3] += w4.x*ev.w; acc[1][4*q+3] += w4.y*ev.w; acc[2][4*q+3] += w4.z*ev.w; acc[3][4*q+3] += w4.w*ev.w;
    }
  }
  float* pp = part + (long)blockIdx.y*131072;
  #pragma unroll
  for (int bb=0;bb<16;bb++){
    float4 o; o.x=acc[0][bb]; o.y=acc[1][bb]; o.z=acc[2][bb]; o.w=acc[3][bb];
    *(float4*)&pp[(b0+bb)*FC1_N + col] = o;
  }
}

// ---- reduce fc2 partials + bias + permuted scatter to out[b][o][n] -------------
__global__ void k_red2(const float* __restrict__ part, const float* __restrict__ bias,
                       float* __restrict__ outp){
  int idx4 = blockIdx.x*256 + threadIdx.x;           // 32768
  float4 a = ((const float4*)bias)[idx4 & 1023];
  #pragma unroll 8
  for (int y=0;y<32;y++){
    float4 p = ((const float4*)(part + (long)y*131072))[idx4];
    a.x+=p.x; a.y+=p.y; a.z+=p.z; a.w+=p.w;
  }
  int idx = idx4*4;
  int b = idx >> 12;
  float av[4] = {a.x, a.y, a.z, a.w};
  #pragma unroll
  for (int c=0;c<4;c++){
    int colf = (idx + c) & 4095;
    int n = colf >> 4, o = colf & 15;
    outp[(b<<12) + (o<<8) + n] = av[c];
  }
}

extern "C" void kernel_launch(void* const* d_in, const int* in_sizes, int n_in,
                              void* d_out, int out_size, void* d_ws, size_t ws_size,
                              hipStream_t stream) {
  const float* data   = (const float*)d_in[0];
  const unsigned char* masks = (const unsigned char*)d_in[1];
  const int* ei       = (const int*)d_in[2];
  const float* gcn_w  = (const float*)d_in[3];
  const float* gcn_b  = (const float*)d_in[4];
  const float* sa_qw  = (const float*)d_in[5];
  const float* sa_qb  = (const float*)d_in[6];
  const float* sa_kw  = (const float*)d_in[7];
  const float* sa_kb  = (const float*)d_in[8];
  const float* wih    = (const float*)d_in[9];
  const float* whh    = (const float*)d_in[10];
  const float* bih    = (const float*)d_in[11];
  const float* bhh    = (const float*)d_in[12];
  const float* ta_qw  = (const float*)d_in[13];
  const float* ta_qb  = (const float*)d_in[14];
  const float* ta_kw  = (const float*)d_in[15];
  const float* ta_kb  = (const float*)d_in[16];
  const float* fc1_w  = (const float*)d_in[17];
  const float* fc1_b  = (const float*)d_in[18];
  const float* fc2_w  = (const float*)d_in[19];
  const float* fc2_b  = (const float*)d_in[20];

  float* dm    = (float*)d_ws;        // 131072
  float* wadj  = dm + 131072;         // 65536
  int*   flags = (int*)(wadj + 65536);// 8
  float* xw    = (float*)(flags + 8); // 524288
  float* hb    = xw + 524288;
  float* qb    = hb + 524288;
  float* kb    = qb + 524288;
  float* gi    = kb + 524288;         // 1572864
  float* rnn   = gi + 1572864;        // 524288
  float* qt    = rnn + 524288;
  float* kt    = qt + 524288;
  float* inter = kt + 524288;         // 131072
  float* part1 = inter + 131072;      // 64*131072
  float* part2 = part1 + 64*131072;   // 32*131072

  float* out_final = (float*)d_out;
  float* out_sa = out_final + 131072;
  float* out_ra = out_final + 655360;

  hipMemsetAsync(wadj, 0, 65536*sizeof(float), stream);
  hipMemsetAsync(flags, 0, 8*sizeof(int), stream);

  k_detect<<<128,256,0,stream>>>(masks, ei, flags);
  k_mask<<<512,256,0,stream>>>(data, masks, flags, dm);
  k_graph<<<1,256,0,stream>>>(ei, flags, wadj);
  k_xw<<<2048,256,0,stream>>>(dm, gcn_w, xw);
  k_agg<<<2048,256,0,stream>>>(wadj, xw, gcn_b, hb);
  k_qk<<<2048,256,0,stream>>>(hb, sa_qw, sa_qb, sa_kw, sa_kb, qb, kb);
  k_attn8<<<1024,256,0,stream>>>(qb, kb, hb, out_sa, 0.0625f);
  k_gi<<<8192,192,0,stream>>>(dm, wih, bih, gi);
  k_gru<<<32,192,0,stream>>>(gi, whh, bhh, rnn);
  k_qk<<<2048,256,0,stream>>>(rnn, ta_qw, ta_qb, ta_kw, ta_kb, qt, kt);
  k_attn8<<<1024,256,0,stream>>>(qt, kt, rnn, out_ra, 0.0625f);
  { dim3 g(4,64); k_fc1<<<g,512,0,stream>>>(fc1_w, rnn, hb, part1); }
  k_red1<<<128,256,0,stream>>>(part1, fc1_b, inter);
  { dim3 g(8,32); k_fc2<<<g,256,0,stream>>>(fc2_w, inter, part2); }
  k_red2<<<128,256,0,stream>>>(part2, fc2_b, out_final);
}

// Round 3
// 561.485 us; speedup vs baseline: 1.2048x; 1.2048x over previous
//
#include <hip/hip_runtime.h>

#define NB 32
#define NN 256
#define NI 16
#define NO 16
#define NC 64
#define NH 64
#define NE 4096
#define FC1_N 4096

__device__ __forceinline__ float sigmoidf_(float x){ return 1.0f/(1.0f+__expf(-x)); }
__device__ __forceinline__ float tanhf_(float x){
  float e = __expf(2.0f*x);
  return 1.0f - 2.0f/(e+1.0f);
}

// ---- runtime dtype detection ------------------------------------------------
__global__ void k_detect(const unsigned char* __restrict__ m8, const int* __restrict__ ei, int* flags){
  int t = blockIdx.x*256 + threadIdx.x;              // 32768 threads
  unsigned a = (unsigned)m8[t*4+1] | (unsigned)m8[t*4+2] | (unsigned)m8[t*4+3];
  if (__any(a != 0) && (threadIdx.x & 63) == 0) atomicOr(&flags[0], 1);
  unsigned b = 0;
  if (t < 4096) b = (unsigned)ei[2*t+1];
  if (__any(b != 0) && (threadIdx.x & 63) == 0) atomicOr(&flags[1], 1);
}

// ---- mask -------------------------------------------------------------------
__global__ void k_mask(const float* __restrict__ data, const unsigned char* __restrict__ m8,
                       const int* __restrict__ flags, float* __restrict__ dm){
  int i = blockIdx.x*256 + threadIdx.x;              // 131072
  int mv = flags[0] ? (int)m8[i] : ((const int*)m8)[i];
  dm[i] = mv ? data[i] : 0.0f;
}

__device__ __forceinline__ int edge_src(const int* ei, const int* flags, int e){
  return flags[1] ? ei[e] : ei[2*e];
}
__device__ __forceinline__ int edge_dst(const int* ei, const int* flags, int e){
  return flags[1] ? ei[NE + e] : ei[2*(NE + e)];
}

// ---- GCN graph prep: zero wadj, degree, dinv, weighted adjacency (one block) --
__global__ __launch_bounds__(256) void k_graph(const int* __restrict__ ei, const int* __restrict__ flags,
                                               float* wadj){
  int t = threadIdx.x;
  float4 z = {0.f,0.f,0.f,0.f};
  for (int x = t; x < 16384; x += 256) ((float4*)wadj)[x] = z;
  __shared__ float degs[NN];
  __shared__ float dls[NN];
  degs[t] = 0.f;
  __syncthreads();
  for (int e = t; e < NE; e += 256) atomicAdd(&degs[edge_dst(ei, flags, e)], 1.0f);
  __syncthreads();
  float di = rsqrtf(degs[t] + 2.0f);
  dls[t] = di;
  atomicAdd(&wadj[t*NN + t], 2.0f*di*di);
  __syncthreads();
  for (int e = t; e < NE; e += 256){
    int s = edge_src(ei, flags, e), d = edge_dst(ei, flags, e);
    atomicAdd(&wadj[d*NN + s], dls[s]*dls[d]);
  }
}

// ---- xw = x @ gcn_w ----------------------------------------------------------
__global__ void k_xw(const float* __restrict__ dm, const float* __restrict__ gw, float* __restrict__ xw){
  int idx = blockIdx.x*256 + threadIdx.x;            // 524288
  int c = idx & 63, n = (idx>>6) & 255, b = idx>>14;
  const float* dmb = dm + b*NI*NN;
  float a = 0.f;
  #pragma unroll
  for (int i=0;i<NI;i++) a += dmb[i*NN + n]*gw[i*NC + c];
  xw[idx] = a;
}

// ---- h = relu(W_adj @ xw + b) -------------------------------------------------
__global__ void k_agg(const float* __restrict__ wadj, const float* __restrict__ xw,
                      const float* __restrict__ gb, float* __restrict__ h){
  int idx = blockIdx.x*256 + threadIdx.x;            // 524288
  int c = idx & 63, n = (idx>>6) & 255, b = idx>>14;
  const float* wr = wadj + n*NN;
  const float* xb = xw + b*NN*NC + c;
  float a = gb[c];
  #pragma unroll 4
  for (int m=0;m<NN;m++) a += wr[m]*xb[m*NC];
  h[idx] = fmaxf(a, 0.0f);
}

// ---- q,k projections, spatial (blocks<2048) + temporal fused -------------------
__global__ void k_qk2(const float* __restrict__ hb, const float* __restrict__ rnn,
    const float* __restrict__ saqw, const float* __restrict__ saqb,
    const float* __restrict__ sakw, const float* __restrict__ sakb,
    const float* __restrict__ taqw, const float* __restrict__ taqb,
    const float* __restrict__ takw, const float* __restrict__ takb,
    float* __restrict__ qb, float* __restrict__ kb, float* __restrict__ qt, float* __restrict__ kt){
  int bid = blockIdx.x;
  const float *src, *qw, *qbias, *kw, *kbias; float *qo, *ko;
  if (bid < 2048){ src=hb; qw=saqw; qbias=saqb; kw=sakw; kbias=sakb; qo=qb; ko=kb; }
  else { bid -= 2048; src=rnn; qw=taqw; qbias=taqb; kw=takw; kbias=takb; qo=qt; ko=kt; }
  int idx = bid*256 + threadIdx.x;
  int c = idx & 63;
  const float* hr = src + (idx>>6)*NC;
  float aq = qbias[c], ak = kbias[c];
  #pragma unroll 8
  for (int cc=0; cc<NC; cc++){ float hv = hr[cc]; aq += hv*qw[cc*NC + c]; ak += hv*kw[cc*NC + c]; }
  qo[idx] = aq; ko[idx] = ak;
}

// ---- fused attention pair: 8 query rows per block, transposed output write -----
__global__ __launch_bounds__(256) void k_attn2(const float* __restrict__ qb, const float* __restrict__ kb,
    const float* __restrict__ hb, const float* __restrict__ qt, const float* __restrict__ kt,
    const float* __restrict__ rnn, float* __restrict__ out_sa, float* __restrict__ out_ra){
  int bidx = blockIdx.x;
  const float *q, *kmat, *v; float* outp;
  if (bidx < 1024){ q=qb; kmat=kb; v=hb; outp=out_sa; }
  else { bidx -= 1024; q=qt; kmat=kt; v=rnn; outp=out_ra; }
  int b = bidx >> 5, n0 = (bidx & 31)*8;
  int t = threadIdx.x;
  const float scale = 0.0625f;
  __shared__ __align__(16) float qs[8][64];
  __shared__ float S[8][256];
  #pragma unroll
  for (int rep=0; rep<2; rep++){
    int j = rep*256 + t; int r = j>>6, c = j&63;
    qs[r][c] = q[((b<<8) + n0 + r)*NC + c];
  }
  __syncthreads();
  float4 kr[16];
  const float4* kp = (const float4*)(kmat + ((b<<8) + t)*NC);
  #pragma unroll
  for (int i=0;i<16;i++) kr[i] = kp[i];
  #pragma unroll
  for (int r=0;r<8;r++){
    const float4* q4 = (const float4*)qs[r];
    float s = 0.f;
    #pragma unroll
    for (int i=0;i<16;i++){ float4 a=q4[i], bb=kr[i]; s += a.x*bb.x + a.y*bb.y + a.z*bb.z + a.w*bb.w; }
    S[r][t] = s*scale;
  }
  __syncthreads();
  {
    int g = t>>5, l = t&31;
    float vals[8];
    #pragma unroll
    for (int k2=0;k2<8;k2++) vals[k2] = S[g][l + (k2<<5)];
    float mx = vals[0];
    #pragma unroll
    for (int k2=1;k2<8;k2++) mx = fmaxf(mx, vals[k2]);
    #pragma unroll
    for (int off=16; off; off>>=1) mx = fmaxf(mx, __shfl_xor(mx, off));
    float sm = 0.f;
    #pragma unroll
    for (int k2=0;k2<8;k2++){ vals[k2] = __expf(vals[k2]-mx); sm += vals[k2]; }
    #pragma unroll
    for (int off=16; off; off>>=1) sm += __shfl_xor(sm, off);
    float rS = 1.0f/sm;
    #pragma unroll
    for (int k2=0;k2<8;k2++) S[g][l + (k2<<5)] = vals[k2]*rS;
  }
  __syncthreads();
  int c = t & 63, rp = t >> 6;
  const float* vp = v + (b<<8)*NC + c;
  float a0 = 0.f, a1 = 0.f;
  #pragma unroll 4
  for (int m=0;m<NN;m++){
    float vv = vp[m*NC];
    a0 += S[rp][m]*vv;
    a1 += S[rp+4][m]*vv;
  }
  outp[(((b<<6)+c)<<8) + n0 + rp]     = a0;
  outp[(((b<<6)+c)<<8) + n0 + rp + 4] = a1;
}

// ---- GRU: gi fused in (dm staged in LDS), one block per sample ----------------
__global__ __launch_bounds__(192) void k_gru(const float* __restrict__ dm,
        const float* __restrict__ wih, const float* __restrict__ bih,
        const float* __restrict__ whh, const float* __restrict__ bhh,
        float* __restrict__ rnn){
  int b = blockIdx.x, j = threadIdx.x;
  __shared__ __align__(16) float dmS[4096];
  __shared__ __align__(16) float hs[64];
  __shared__ float gh[192];
  __shared__ float gin[64];
  float wh[64];
  const float4* wr = (const float4*)(whh + j*NH);
  #pragma unroll
  for (int k4=0;k4<16;k4++){ float4 t4 = wr[k4]; wh[4*k4]=t4.x; wh[4*k4+1]=t4.y; wh[4*k4+2]=t4.z; wh[4*k4+3]=t4.w; }
  float wi[16];
  const float4* wir = (const float4*)(wih + j*NI);
  #pragma unroll
  for (int k4=0;k4<4;k4++){ float4 t4 = wir[k4]; wi[4*k4]=t4.x; wi[4*k4+1]=t4.y; wi[4*k4+2]=t4.z; wi[4*k4+3]=t4.w; }
  float bj = bhh[j], bij = bih[j];
  const float4* dmb4 = (const float4*)(dm + b*4096);
  for (int x = j; x < 1024; x += 192) ((float4*)dmS)[x] = dmb4[x];
  if (j < 64) hs[j] = 0.f;
  __syncthreads();
  for (int t=0;t<NN;t++){
    const float* xt = &dmS[t*16];
    float gival = bij;
    #pragma unroll
    for (int i=0;i<16;i++) gival += wi[i]*xt[i];
    float a0=0.f,a1=0.f,a2=0.f,a3=0.f;
    #pragma unroll
    for (int k4=0;k4<16;k4++){
      float4 hv = *(const float4*)&hs[4*k4];
      a0 += wh[4*k4+0]*hv.x; a1 += wh[4*k4+1]*hv.y; a2 += wh[4*k4+2]*hv.z; a3 += wh[4*k4+3]*hv.w;
    }
    float ghv = a0+a1+a2+a3+bj;
    if (j < 128) gh[j] = ghv + gival;
    else { gh[j] = ghv; gin[j-128] = gival; }
    __syncthreads();
    if (j < 64){
      float r  = sigmoidf_(gh[j]);
      float z  = sigmoidf_(gh[j+64]);
      float nn = tanhf_   (gin[j] + r*gh[j+128]);
      float hn = nn + z*(hs[j]-nn);
      rnn[(b*NN + t)*NH + j] = hn;
      hs[j] = hn;
    }
    __syncthreads();
  }
}

// ---- E_T[32768][32]: transposed embed = concat([rnn_out, se]) ------------------
__global__ void k_embedT(const float* __restrict__ rnn, const float* __restrict__ h,
                         float* __restrict__ ET){
  int idx = blockIdx.x*256 + threadIdx.x;            // 1048576
  int bb = idx & 31, rr = idx >> 5;
  int n = rr >> 7, c = rr & 127;
  float v;
  if (c < 64) v = rnn[((bb<<8) + n)*NH + c];
  else { int f = (n<<6) + (c-64); v = h[(bb<<14) + ((f&255)<<6) + (f>>8)]; }
  ET[idx] = v;
}

#define FMAQ(q, ev) { \
  acc[0][4*q+0]+=wv.x*ev.x; acc[1][4*q+0]+=wv.y*ev.x; acc[2][4*q+0]+=wv.z*ev.x; acc[3][4*q+0]+=wv.w*ev.x; \
  acc[0][4*q+1]+=wv.x*ev.y; acc[1][4*q+1]+=wv.y*ev.y; acc[2][4*q+1]+=wv.z*ev.y; acc[3][4*q+1]+=wv.w*ev.y; \
  acc[0][4*q+2]+=wv.x*ev.z; acc[1][4*q+2]+=wv.y*ev.z; acc[2][4*q+2]+=wv.z*ev.z; acc[3][4*q+2]+=wv.w*ev.z; \
  acc[0][4*q+3]+=wv.x*ev.w; acc[1][4*q+3]+=wv.y*ev.w; acc[2][4*q+3]+=wv.z*ev.w; acc[3][4*q+3]+=wv.w*ev.w; }

// ---- fc1: E[32][32768] @ W[32768][4096], wave-private LDS, PF=4 W-ring ---------
// grid (4, 128), block 512 = 4 col-waves x 2 batch-halves. 256 rows/block.
__global__ __launch_bounds__(512, 4) void k_fc1(const float* __restrict__ W,
                       const float* __restrict__ ET, float* __restrict__ part){
  const int tid = threadIdx.x, lane = tid & 63, w = tid >> 6;
  const int cw = w & 3, bh = w >> 2;
  const int col = blockIdx.x*1024 + cw*256 + lane*4;
  const int i0 = blockIdx.y*256;
  __shared__ __align__(16) float es[8][128*16];      // 64 KB, wave-private slices
  float4* esw4 = (float4*)es[w];
  float acc[4][16];
  #pragma unroll
  for (int c=0;c<4;c++)
    #pragma unroll
    for (int bb=0;bb<16;bb++) acc[c][bb]=0.f;
  const float* wp = W + (long)i0*FC1_N + col;
  float4 ring[4];
  #pragma unroll
  for (int p=0;p<4;p++) ring[p] = *(const float4*)(wp + (long)p*FC1_N);
  const float4* ET4 = (const float4*)ET;
  for (int c=0;c<2;c++){
    __syncthreads();                                  // drift control only
    const int rowbase = i0 + c*128;
    #pragma unroll
    for (int k=0;k<8;k++){
      int j = lane + k*64;                            // float4 index within chunk
      esw4[j] = ET4[(long)(rowbase + (j>>2))*8 + bh*4 + (j&3)];
    }
    for (int ii4=0; ii4<32; ii4++){
      #pragma unroll
      for (int p=0;p<4;p++){
        const int r = c*128 + ii4*4 + p;
        float4 wv = ring[p];
        int pf = r + 4; pf = (pf < 256) ? pf : 255;
        ring[p] = *(const float4*)(wp + (long)pf*FC1_N);
        const int ib = (ii4*4 + p)*4;
        float4 e0 = esw4[ib+0], e1 = esw4[ib+1], e2 = esw4[ib+2], e3 = esw4[ib+3];
        FMAQ(0, e0) FMAQ(1, e1) FMAQ(2, e2) FMAQ(3, e3)
      }
    }
  }
  float* pp = part + (long)blockIdx.y*131072 + (long)(bh*16)*FC1_N + col;
  #pragma unroll
  for (int bb=0;bb<16;bb++){
    float4 o; o.x=acc[0][bb]; o.y=acc[1][bb]; o.z=acc[2][bb]; o.w=acc[3][bb];
    *(float4*)(pp + (long)bb*FC1_N) = o;
  }
}

// ---- reduce fc1 partials (128) + bias -> interT[4096][32] ----------------------
__global__ void k_red1(const float* __restrict__ part, const float* __restrict__ bias,
                       float* __restrict__ ITr){
  int idx = blockIdx.x*256 + threadIdx.x;            // 131072
  int b = idx >> 12, col = idx & 4095;
  float a = bias[col];
  #pragma unroll 16
  for (int y=0;y<128;y++) a += part[(long)y*131072 + b*FC1_N + col];
  ITr[col*32 + b] = a;
}

// ---- fc2: inter[32][4096] @ W[4096][4096] --------------------------------------
// grid (16, 64), block 256 = 1 col-wave x 4 batch-quarters. 64 rows/block.
__global__ __launch_bounds__(256, 4) void k_fc2(const float* __restrict__ W,
                       const float* __restrict__ ITr, float* __restrict__ part){
  const int tid = threadIdx.x, lane = tid & 63, bq = tid >> 6;
  const int col = blockIdx.x*256 + lane*4;
  const int i0 = blockIdx.y*64;
  __shared__ __align__(16) float es[4][64*8];        // 8 KB, wave-private
  float4* esw4 = (float4*)es[bq];
  float acc[4][8];
  #pragma unroll
  for (int c=0;c<4;c++)
    #pragma unroll
    for (int bb=0;bb<8;bb++) acc[c][bb]=0.f;
  const float4* IT4 = (const float4*)ITr;
  #pragma unroll
  for (int k=0;k<2;k++){
    int j = lane + k*64;                              // float4 index (128 total)
    esw4[j] = IT4[(i0 + (j>>1))*8 + bq*2 + (j&1)];
  }
  const float* wp = W + (long)i0*FC1_N + col;
  float4 ring[4];
  #pragma unroll
  for (int p=0;p<4;p++) ring[p] = *(const float4*)(wp + (long)p*FC1_N);
  for (int ii4=0; ii4<16; ii4++){
    #pragma unroll
    for (int p=0;p<4;p++){
      const int r = ii4*4 + p;
      float4 wv = ring[p];
      int pf = r + 4; pf = (pf < 64) ? pf : 63;
      ring[p] = *(const float4*)(wp + (long)pf*FC1_N);
      float4 e0 = esw4[r*2+0], e1 = esw4[r*2+1];
      FMAQ(0, e0) FMAQ(1, e1)
    }
  }
  float* pp = part + (long)blockIdx.y*131072 + (long)(bq*8)*FC1_N + col;
  #pragma unroll
  for (int bb=0;bb<8;bb++){
    float4 o; o.x=acc[0][bb]; o.y=acc[1][bb]; o.z=acc[2][bb]; o.w=acc[3][bb];
    *(float4*)(pp + (long)bb*FC1_N) = o;
  }
}

// ---- reduce fc2 partials (64) + bias + permuted write to out[b][o][n] ----------
__global__ void k_red2(const float* __restrict__ part, const float* __restrict__ bias,
                       float* __restrict__ outp){
  int idx = blockIdx.x*256 + threadIdx.x;            // 131072
  int b = idx >> 12, col = idx & 4095;
  float a = bias[col];
  #pragma unroll 16
  for (int y=0;y<64;y++) a += part[(long)y*131072 + b*FC1_N + col];
  int n = col >> 4, o = col & 15;
  outp[(b<<12) + (o<<8) + n] = a;
}

extern "C" void kernel_launch(void* const* d_in, const int* in_sizes, int n_in,
                              void* d_out, int out_size, void* d_ws, size_t ws_size,
                              hipStream_t stream) {
  const float* data   = (const float*)d_in[0];
  const unsigned char* masks = (const unsigned char*)d_in[1];
  const int* ei       = (const int*)d_in[2];
  const float* gcn_w  = (const float*)d_in[3];
  const float* gcn_b  = (const float*)d_in[4];
  const float* sa_qw  = (const float*)d_in[5];
  const float* sa_qb  = (const float*)d_in[6];
  const float* sa_kw  = (const float*)d_in[7];
  const float* sa_kb  = (const float*)d_in[8];
  const float* wih    = (const float*)d_in[9];
  const float* whh    = (const float*)d_in[10];
  const float* bih    = (const float*)d_in[11];
  const float* bhh    = (const float*)d_in[12];
  const float* ta_qw  = (const float*)d_in[13];
  const float* ta_qb  = (const float*)d_in[14];
  const float* ta_kw  = (const float*)d_in[15];
  const float* ta_kb  = (const float*)d_in[16];
  const float* fc1_w  = (const float*)d_in[17];
  const float* fc1_b  = (const float*)d_in[18];
  const float* fc2_w  = (const float*)d_in[19];
  const float* fc2_b  = (const float*)d_in[20];

  float* dm    = (float*)d_ws;        // 131072
  float* wadj  = dm + 131072;         // 65536
  int*   flags = (int*)(wadj + 65536);// 8
  float* xw    = (float*)(flags + 8); // 524288
  float* hb    = xw + 524288;
  float* qb    = hb + 524288;
  float* kb    = qb + 524288;
  float* rnn   = kb + 524288;
  float* qt    = rnn + 524288;
  float* kt    = qt + 524288;
  float* ET    = kt + 524288;         // 1048576
  float* ITr   = ET + 1048576;        // 131072
  float* part1 = ITr + 131072;        // 128*131072
  float* part2 = part1 + 128*131072;  // 64*131072

  float* out_final = (float*)d_out;
  float* out_sa = out_final + 131072;
  float* out_ra = out_final + 655360;

  hipMemsetAsync(flags, 0, 32, stream);

  k_detect<<<128,256,0,stream>>>(masks, ei, flags);
  k_mask<<<512,256,0,stream>>>(data, masks, flags, dm);
  k_graph<<<1,256,0,stream>>>(ei, flags, wadj);
  k_xw<<<2048,256,0,stream>>>(dm, gcn_w, xw);
  k_gru<<<32,192,0,stream>>>(dm, wih, bih, whh, bhh, rnn);
  k_agg<<<2048,256,0,stream>>>(wadj, xw, gcn_b, hb);
  k_qk2<<<4096,256,0,stream>>>(hb, rnn, sa_qw, sa_qb, sa_kw, sa_kb,
                               ta_qw, ta_qb, ta_kw, ta_kb, qb, kb, qt, kt);
  k_attn2<<<2048,256,0,stream>>>(qb, kb, hb, qt, kt, rnn, out_sa, out_ra);
  k_embedT<<<4096,256,0,stream>>>(rnn, hb, ET);
  { dim3 g(4,128); k_fc1<<<g,512,0,stream>>>(fc1_w, ET, part1); }
  k_red1<<<512,256,0,stream>>>(part1, fc1_b, ITr);
  { dim3 g(16,64); k_fc2<<<g,256,0,stream>>>(fc2_w, ITr, part2); }
  k_red2<<<512,256,0,stream>>>(part2, fc2_b, out_final);
}

// Round 4
// 504.349 us; speedup vs baseline: 1.3413x; 1.1133x over previous
//
#include <hip/hip_runtime.h>

#define NB 32
#define NN 256
#define NI 16
#define NO 16
#define NC 64
#define NH 64
#define NE 4096
#define FC1_N 4096

__device__ __forceinline__ float sigmoidf_(float x){ return 1.0f/(1.0f+__expf(-x)); }
__device__ __forceinline__ float tanhf_(float x){
  float e = __expf(2.0f*x);
  return 1.0f - 2.0f/(e+1.0f);
}

// async global->LDS, 16B per lane (lane i lands at ldsbase + i*16)
__device__ __forceinline__ void gload16(const void* g, void* l){
  __builtin_amdgcn_global_load_lds((const __attribute__((address_space(1))) void*)g,
                                   (__attribute__((address_space(3))) void*)l, 16, 0, 0);
}

// ---- runtime dtype detection ------------------------------------------------
__global__ void k_detect(const unsigned char* __restrict__ m8, const int* __restrict__ ei, int* flags){
  int t = blockIdx.x*256 + threadIdx.x;              // 32768 threads
  unsigned a = (unsigned)m8[t*4+1] | (unsigned)m8[t*4+2] | (unsigned)m8[t*4+3];
  if (__any(a != 0) && (threadIdx.x & 63) == 0) atomicOr(&flags[0], 1);
  unsigned b = 0;
  if (t < 4096) b = (unsigned)ei[2*t+1];
  if (__any(b != 0) && (threadIdx.x & 63) == 0) atomicOr(&flags[1], 1);
}

// ---- mask -------------------------------------------------------------------
__global__ void k_mask(const float* __restrict__ data, const unsigned char* __restrict__ m8,
                       const int* __restrict__ flags, float* __restrict__ dm){
  int i = blockIdx.x*256 + threadIdx.x;              // 131072
  int mv = flags[0] ? (int)m8[i] : ((const int*)m8)[i];
  dm[i] = mv ? data[i] : 0.0f;
}

__device__ __forceinline__ int edge_src(const int* ei, const int* flags, int e){
  return flags[1] ? ei[e] : ei[2*e];
}
__device__ __forceinline__ int edge_dst(const int* ei, const int* flags, int e){
  return flags[1] ? ei[NE + e] : ei[2*(NE + e)];
}

// ---- GCN graph prep: zero wadj, degree, dinv, weighted adjacency (one block) --
__global__ __launch_bounds__(256) void k_graph(const int* __restrict__ ei, const int* __restrict__ flags,
                                               float* wadj){
  int t = threadIdx.x;
  float4 z = {0.f,0.f,0.f,0.f};
  for (int x = t; x < 16384; x += 256) ((float4*)wadj)[x] = z;
  __shared__ float degs[NN];
  __shared__ float dls[NN];
  degs[t] = 0.f;
  __syncthreads();
  for (int e = t; e < NE; e += 256) atomicAdd(&degs[edge_dst(ei, flags, e)], 1.0f);
  __syncthreads();
  float di = rsqrtf(degs[t] + 2.0f);
  dls[t] = di;
  atomicAdd(&wadj[t*NN + t], 2.0f*di*di);
  __syncthreads();
  for (int e = t; e < NE; e += 256){
    int s = edge_src(ei, flags, e), d = edge_dst(ei, flags, e);
    atomicAdd(&wadj[d*NN + s], dls[s]*dls[d]);
  }
}

// ---- xw = x @ gcn_w ----------------------------------------------------------
__global__ void k_xw(const float* __restrict__ dm, const float* __restrict__ gw, float* __restrict__ xw){
  int idx = blockIdx.x*256 + threadIdx.x;            // 524288
  int c = idx & 63, n = (idx>>6) & 255, b = idx>>14;
  const float* dmb = dm + b*NI*NN;
  float a = 0.f;
  #pragma unroll
  for (int i=0;i<NI;i++) a += dmb[i*NN + n]*gw[i*NC + c];
  xw[idx] = a;
}

// ---- h = relu(W_adj @ xw + b) -------------------------------------------------
__global__ void k_agg(const float* __restrict__ wadj, const float* __restrict__ xw,
                      const float* __restrict__ gb, float* __restrict__ h){
  int idx = blockIdx.x*256 + threadIdx.x;            // 524288
  int c = idx & 63, n = (idx>>6) & 255, b = idx>>14;
  const float* wr = wadj + n*NN;
  const float* xb = xw + b*NN*NC + c;
  float a = gb[c];
  #pragma unroll 4
  for (int m=0;m<NN;m++) a += wr[m]*xb[m*NC];
  h[idx] = fmaxf(a, 0.0f);
}

// ---- q,k projections, spatial (blocks<2048) + temporal fused -------------------
__global__ void k_qk2(const float* __restrict__ hb, const float* __restrict__ rnn,
    const float* __restrict__ saqw, const float* __restrict__ saqb,
    const float* __restrict__ sakw, const float* __restrict__ sakb,
    const float* __restrict__ taqw, const float* __restrict__ taqb,
    const float* __restrict__ takw, const float* __restrict__ takb,
    float* __restrict__ qb, float* __restrict__ kb, float* __restrict__ qt, float* __restrict__ kt){
  int bid = blockIdx.x;
  const float *src, *qw, *qbias, *kw, *kbias; float *qo, *ko;
  if (bid < 2048){ src=hb; qw=saqw; qbias=saqb; kw=sakw; kbias=sakb; qo=qb; ko=kb; }
  else { bid -= 2048; src=rnn; qw=taqw; qbias=taqb; kw=takw; kbias=takb; qo=qt; ko=kt; }
  int idx = bid*256 + threadIdx.x;
  int c = idx & 63;
  const float* hr = src + (idx>>6)*NC;
  float aq = qbias[c], ak = kbias[c];
  #pragma unroll 8
  for (int cc=0; cc<NC; cc++){ float hv = hr[cc]; aq += hv*qw[cc*NC + c]; ak += hv*kw[cc*NC + c]; }
  qo[idx] = aq; ko[idx] = ak;
}

// ---- fused attention pair: 8 query rows per block, transposed output write -----
__global__ __launch_bounds__(256) void k_attn2(const float* __restrict__ qb, const float* __restrict__ kb,
    const float* __restrict__ hb, const float* __restrict__ qt, const float* __restrict__ kt,
    const float* __restrict__ rnn, float* __restrict__ out_sa, float* __restrict__ out_ra){
  int bidx = blockIdx.x;
  const float *q, *kmat, *v; float* outp;
  if (bidx < 1024){ q=qb; kmat=kb; v=hb; outp=out_sa; }
  else { bidx -= 1024; q=qt; kmat=kt; v=rnn; outp=out_ra; }
  int b = bidx >> 5, n0 = (bidx & 31)*8;
  int t = threadIdx.x;
  const float scale = 0.0625f;
  __shared__ __align__(16) float qs[8][64];
  __shared__ float S[8][256];
  #pragma unroll
  for (int rep=0; rep<2; rep++){
    int j = rep*256 + t; int r = j>>6, c = j&63;
    qs[r][c] = q[((b<<8) + n0 + r)*NC + c];
  }
  __syncthreads();
  float4 kr[16];
  const float4* kp = (const float4*)(kmat + ((b<<8) + t)*NC);
  #pragma unroll
  for (int i=0;i<16;i++) kr[i] = kp[i];
  #pragma unroll
  for (int r=0;r<8;r++){
    const float4* q4 = (const float4*)qs[r];
    float s = 0.f;
    #pragma unroll
    for (int i=0;i<16;i++){ float4 a=q4[i], bb=kr[i]; s += a.x*bb.x + a.y*bb.y + a.z*bb.z + a.w*bb.w; }
    S[r][t] = s*scale;
  }
  __syncthreads();
  {
    int g = t>>5, l = t&31;
    float vals[8];
    #pragma unroll
    for (int k2=0;k2<8;k2++) vals[k2] = S[g][l + (k2<<5)];
    float mx = vals[0];
    #pragma unroll
    for (int k2=1;k2<8;k2++) mx = fmaxf(mx, vals[k2]);
    #pragma unroll
    for (int off=16; off; off>>=1) mx = fmaxf(mx, __shfl_xor(mx, off));
    float sm = 0.f;
    #pragma unroll
    for (int k2=0;k2<8;k2++){ vals[k2] = __expf(vals[k2]-mx); sm += vals[k2]; }
    #pragma unroll
    for (int off=16; off; off>>=1) sm += __shfl_xor(sm, off);
    float rS = 1.0f/sm;
    #pragma unroll
    for (int k2=0;k2<8;k2++) S[g][l + (k2<<5)] = vals[k2]*rS;
  }
  __syncthreads();
  int c = t & 63, rp = t >> 6;
  const float* vp = v + (b<<8)*NC + c;
  float a0 = 0.f, a1 = 0.f;
  #pragma unroll 4
  for (int m=0;m<NN;m++){
    float vv = vp[m*NC];
    a0 += S[rp][m]*vv;
    a1 += S[rp+4][m]*vv;
  }
  outp[(((b<<6)+c)<<8) + n0 + rp]     = a0;
  outp[(((b<<6)+c)<<8) + n0 + rp + 4] = a1;
}

// ---- GRU: gi fused in (dm staged in LDS), one block per sample ----------------
__global__ __launch_bounds__(192) void k_gru(const float* __restrict__ dm,
        const float* __restrict__ wih, const float* __restrict__ bih,
        const float* __restrict__ whh, const float* __restrict__ bhh,
        float* __restrict__ rnn){
  int b = blockIdx.x, j = threadIdx.x;
  __shared__ __align__(16) float dmS[4096];
  __shared__ __align__(16) float hs[64];
  __shared__ float gh[192];
  __shared__ float gin[64];
  float wh[64];
  const float4* wr = (const float4*)(whh + j*NH);
  #pragma unroll
  for (int k4=0;k4<16;k4++){ float4 t4 = wr[k4]; wh[4*k4]=t4.x; wh[4*k4+1]=t4.y; wh[4*k4+2]=t4.z; wh[4*k4+3]=t4.w; }
  float wi[16];
  const float4* wir = (const float4*)(wih + j*NI);
  #pragma unroll
  for (int k4=0;k4<4;k4++){ float4 t4 = wir[k4]; wi[4*k4]=t4.x; wi[4*k4+1]=t4.y; wi[4*k4+2]=t4.z; wi[4*k4+3]=t4.w; }
  float bj = bhh[j], bij = bih[j];
  const float4* dmb4 = (const float4*)(dm + b*4096);
  for (int x = j; x < 1024; x += 192) ((float4*)dmS)[x] = dmb4[x];
  if (j < 64) hs[j] = 0.f;
  __syncthreads();
  for (int t=0;t<NN;t++){
    const float* xt = &dmS[t*16];
    float gival = bij;
    #pragma unroll
    for (int i=0;i<16;i++) gival += wi[i]*xt[i];
    float a0=0.f,a1=0.f,a2=0.f,a3=0.f;
    #pragma unroll
    for (int k4=0;k4<16;k4++){
      float4 hv = *(const float4*)&hs[4*k4];
      a0 += wh[4*k4+0]*hv.x; a1 += wh[4*k4+1]*hv.y; a2 += wh[4*k4+2]*hv.z; a3 += wh[4*k4+3]*hv.w;
    }
    float ghv = a0+a1+a2+a3+bj;
    if (j < 128) gh[j] = ghv + gival;
    else { gh[j] = ghv; gin[j-128] = gival; }
    __syncthreads();
    if (j < 64){
      float r  = sigmoidf_(gh[j]);
      float z  = sigmoidf_(gh[j+64]);
      float nn = tanhf_   (gin[j] + r*gh[j+128]);
      float hn = nn + z*(hs[j]-nn);
      rnn[(b*NN + t)*NH + j] = hn;
      hs[j] = hn;
    }
    __syncthreads();
  }
}

// ---- E_T[32768][32]: transposed embed = concat([rnn_out, se]) ------------------
__global__ void k_embedT(const float* __restrict__ rnn, const float* __restrict__ h,
                         float* __restrict__ ET){
  int idx = blockIdx.x*256 + threadIdx.x;            // 1048576
  int bb = idx & 31, rr = idx >> 5;
  int n = rr >> 7, c = rr & 127;
  float v;
  if (c < 64) v = rnn[((bb<<8) + n)*NH + c];
  else { int f = (n<<6) + (c-64); v = h[(bb<<14) + ((f&255)<<6) + (f>>8)]; }
  ET[idx] = v;
}

// ---- fc GEMM: C[32][4096] partial = E[32][K-slice] @ W[K-slice][4096] ----------
// block 512 thr = 8 waves (2 col-waves x 4 batch-quarters); chunk = 8 rows x 512 cols,
// double-buffered LDS via global_load_lds; grid (8, K/KC).
template<int KC>
__global__ __launch_bounds__(512, 4) void k_fc(const float* __restrict__ W,
        const float* __restrict__ Ein, float* __restrict__ part){
  const int tid = threadIdx.x, lane = tid & 63, wv_ = tid >> 6;
  const int cw = wv_ & 1, bq = wv_ >> 1;
  const int c0 = blockIdx.x*512;
  const long k0 = (long)blockIdx.y*KC;
  __shared__ __align__(16) float wlds[2][8][512];    // 32 KB
  __shared__ __align__(16) float elds[2][256];       // 2 KB
  float acc[4][8];
  #pragma unroll
  for (int c=0;c<4;c++)
    #pragma unroll
    for (int bb=0;bb<8;bb++) acc[c][bb]=0.f;

  const int NCH = KC/8;
  #define STAGE_FC(ch, bf) { \
    const float* wsrc = W + (k0 + (long)(ch)*8)*FC1_N + c0; \
    gload16(wsrc + (long)wv_*FC1_N + lane*4,       &wlds[bf][wv_][0]); \
    gload16(wsrc + (long)wv_*FC1_N + 256 + lane*4, &wlds[bf][wv_][256]); \
    if (wv_ == 0) gload16(Ein + (k0 + (long)(ch)*8)*32 + lane*4, &elds[bf][0]); \
  }

  STAGE_FC(0, 0)
  int cur = 0;
  for (int ch=0; ch<NCH; ch++){
    __syncthreads();                                  // drains this wave's DMA (vmcnt) + all waves
    if (ch+1 < NCH) STAGE_FC(ch+1, cur^1)
    #pragma unroll
    for (int r=0;r<8;r++){
      float4 wv4 = *(const float4*)&wlds[cur][r][cw*256 + lane*4];
      float4 e0 = *(const float4*)&elds[cur][r*32 + bq*8];
      float4 e1 = *(const float4*)&elds[cur][r*32 + bq*8 + 4];
      float ev[8] = {e0.x,e0.y,e0.z,e0.w,e1.x,e1.y,e1.z,e1.w};
      #pragma unroll
      for (int bb=0;bb<8;bb++){
        acc[0][bb] += wv4.x*ev[bb];
        acc[1][bb] += wv4.y*ev[bb];
        acc[2][bb] += wv4.z*ev[bb];
        acc[3][bb] += wv4.w*ev[bb];
      }
    }
    cur ^= 1;
  }
  float* pp = part + (long)blockIdx.y*131072 + (long)(bq*8)*FC1_N + c0 + cw*256 + lane*4;
  #pragma unroll
  for (int bb=0;bb<8;bb++){
    float4 o; o.x=acc[0][bb]; o.y=acc[1][bb]; o.z=acc[2][bb]; o.w=acc[3][bb];
    *(float4*)(pp + (long)bb*FC1_N) = o;
  }
  #undef STAGE_FC
}

// ---- reduce fc1 partials (64) + bias -> interT[4096][32] ----------------------
__global__ void k_red1(const float* __restrict__ part, const float* __restrict__ bias,
                       float* __restrict__ ITr){
  int idx = blockIdx.x*256 + threadIdx.x;            // 131072
  int b = idx >> 12, col = idx & 4095;
  float a = bias[col];
  #pragma unroll 16
  for (int y=0;y<64;y++) a += part[(long)y*131072 + b*FC1_N + col];
  ITr[col*32 + b] = a;
}

// ---- reduce fc2 partials (64) + bias + permuted write to out[b][o][n] ----------
__global__ void k_red2(const float* __restrict__ part, const float* __restrict__ bias,
                       float* __restrict__ outp){
  int idx = blockIdx.x*256 + threadIdx.x;            // 131072
  int b = idx >> 12, col = idx & 4095;
  float a = bias[col];
  #pragma unroll 16
  for (int y=0;y<64;y++) a += part[(long)y*131072 + b*FC1_N + col];
  int n = col >> 4, o = col & 15;
  outp[(b<<12) + (o<<8) + n] = a;
}

extern "C" void kernel_launch(void* const* d_in, const int* in_sizes, int n_in,
                              void* d_out, int out_size, void* d_ws, size_t ws_size,
                              hipStream_t stream) {
  const float* data   = (const float*)d_in[0];
  const unsigned char* masks = (const unsigned char*)d_in[1];
  const int* ei       = (const int*)d_in[2];
  const float* gcn_w  = (const float*)d_in[3];
  const float* gcn_b  = (const float*)d_in[4];
  const float* sa_qw  = (const float*)d_in[5];
  const float* sa_qb  = (const float*)d_in[6];
  const float* sa_kw  = (const float*)d_in[7];
  const float* sa_kb  = (const float*)d_in[8];
  const float* wih    = (const float*)d_in[9];
  const float* whh    = (const float*)d_in[10];
  const float* bih    = (const float*)d_in[11];
  const float* bhh    = (const float*)d_in[12];
  const float* ta_qw  = (const float*)d_in[13];
  const float* ta_qb  = (const float*)d_in[14];
  const float* ta_kw  = (const float*)d_in[15];
  const float* ta_kb  = (const float*)d_in[16];
  const float* fc1_w  = (const float*)d_in[17];
  const float* fc1_b  = (const float*)d_in[18];
  const float* fc2_w  = (const float*)d_in[19];
  const float* fc2_b  = (const float*)d_in[20];

  float* dm    = (float*)d_ws;        // 131072
  float* wadj  = dm + 131072;         // 65536
  int*   flags = (int*)(wadj + 65536);// 8
  float* xw    = (float*)(flags + 8); // 524288
  float* hb    = xw + 524288;
  float* qb    = hb + 524288;
  float* kb    = qb + 524288;
  float* rnn   = kb + 524288;
  float* qt    = rnn + 524288;
  float* kt    = qt + 524288;
  float* ET    = kt + 524288;         // 1048576
  float* ITr   = ET + 1048576;        // 131072
  float* part1 = ITr + 131072;        // 64*131072
  float* part2 = part1 + 64*131072;   // 64*131072

  float* out_final = (float*)d_out;
  float* out_sa = out_final + 131072;
  float* out_ra = out_final + 655360;

  hipMemsetAsync(flags, 0, 32, stream);

  k_detect<<<128,256,0,stream>>>(masks, ei, flags);
  k_mask<<<512,256,0,stream>>>(data, masks, flags, dm);
  k_graph<<<1,256,0,stream>>>(ei, flags, wadj);
  k_xw<<<2048,256,0,stream>>>(dm, gcn_w, xw);
  k_gru<<<32,192,0,stream>>>(dm, wih, bih, whh, bhh, rnn);
  k_agg<<<2048,256,0,stream>>>(wadj, xw, gcn_b, hb);
  k_qk2<<<4096,256,0,stream>>>(hb, rnn, sa_qw, sa_qb, sa_kw, sa_kb,
                               ta_qw, ta_qb, ta_kw, ta_kb, qb, kb, qt, kt);
  k_attn2<<<2048,256,0,stream>>>(qb, kb, hb, qt, kt, rnn, out_sa, out_ra);
  k_embedT<<<4096,256,0,stream>>>(rnn, hb, ET);
  { dim3 g(8,64); k_fc<512><<<g,512,0,stream>>>(fc1_w, ET, part1); }
  k_red1<<<512,256,0,stream>>>(part1, fc1_b, ITr);
  { dim3 g(8,64); k_fc<64><<<g,512,0,stream>>>(fc2_w, ITr, part2); }
  k_red2<<<512,256,0,stream>>>(part2, fc2_b, out_final);
}